// Round 2
// baseline (1056.994 us; speedup 1.0000x reference)
//
#include <hip/hip_runtime.h>
#include <cstdint>
#include <cstddef>

#define NN 1000
#define EE 128000
#define HIDD 512
#define NH 8
#define CHN 64
#define LAYERS 6
#define SCALE 0.125f

// ---------------- sort-by-target (counting sort) ----------------
__global__ void zero_counts(int* cnt){
    cnt[threadIdx.x] = 0;   // buffer is 1024 ints
}

__global__ void hist_kernel(const int* __restrict__ tgt, int* cnt){
    int e = blockIdx.x*256 + threadIdx.x;
    if (e < EE) atomicAdd(&cnt[tgt[e]], 1);
}

__global__ void scan_kernel(const int* __restrict__ cnt, int* offs, int* cursor){
    __shared__ int s[1024];
    int tid = threadIdx.x;
    s[tid] = (tid < NN) ? cnt[tid] : 0;
    __syncthreads();
    for (int st = 1; st < 1024; st <<= 1){
        int v = (tid >= st) ? s[tid-st] : 0;
        __syncthreads();
        s[tid] += v;
        __syncthreads();
    }
    int excl = (tid == 0) ? 0 : s[tid-1];
    if (tid < NN){ offs[tid] = excl; cursor[tid] = excl; }
    if (tid == 0) offs[NN] = s[NN-1];
}

__global__ void scatter_kernel(const int* __restrict__ src, const int* __restrict__ tgt,
                               int* cursor, int* ssrc, int* seid){
    int e = blockIdx.x*256 + threadIdx.x;
    if (e < EE){
        int t = tgt[e];
        int pos = atomicAdd(&cursor[t], 1);
        ssrc[pos] = src[e];
        seid[pos] = e;
    }
}

// ---------------- edge encoder: 4 -> 16 -> 32 ----------------
__global__ __launch_bounds__(256) void edge_enc(
    const float* __restrict__ edge_attr,
    const float* __restrict__ w1, const float* __restrict__ b1,
    const float* __restrict__ w2, const float* __restrict__ b2,
    float* __restrict__ ef)
{
    __shared__ float w1s[64], b1s[16], w2s[512], b2s[32];
    int tid = threadIdx.x;
    if (tid < 64) w1s[tid] = w1[tid];
    if (tid < 16) b1s[tid] = b1[tid];
    if (tid < 32) b2s[tid] = b2[tid];
    w2s[tid] = w2[tid];
    w2s[tid+256] = w2[tid+256];
    __syncthreads();
    int e = blockIdx.x*256 + tid;
    if (e >= EE) return;
    float4 av = *(const float4*)(edge_attr + (size_t)e*4);
    float hd[16];
    #pragma unroll
    for (int i = 0; i < 16; i++){
        float v = av.x*w1s[i] + av.y*w1s[16+i] + av.z*w1s[32+i] + av.w*w1s[48+i] + b1s[i];
        hd[i] = fmaxf(v, 0.f);
    }
    float outv[32];
    #pragma unroll
    for (int k = 0; k < 32; k++){
        float v = b2s[k];
        #pragma unroll
        for (int i = 0; i < 16; i++) v += hd[i]*w2s[i*32+k];
        outv[k] = v;
    }
    float* op = ef + (size_t)e*32;
    #pragma unroll
    for (int k4 = 0; k4 < 8; k4++){
        *(float4*)(op + k4*4) = make_float4(outv[k4*4], outv[k4*4+1], outv[k4*4+2], outv[k4*4+3]);
    }
}

// ---------------- tiled fp32 GEMM: C = A@W + bias (+pe) ----------------
// BM=BN=64, BK=16, 256 threads, 4x4 per thread
__global__ __launch_bounds__(256) void gemm_embed(
    const float* __restrict__ A, const float* __restrict__ W,
    const float* __restrict__ bias, const float* __restrict__ pe,
    float* __restrict__ C, int M, int Nn, int Kk)
{
    __shared__ float As[16*68];
    __shared__ float Bs[16*64];
    int tid = threadIdx.x;
    int tx = tid & 15, ty = tid >> 4;
    int row0 = blockIdx.y*64, col0 = blockIdx.x*64;
    float acc[4][4] = {};
    for (int k0 = 0; k0 < Kk; k0 += 16){
        #pragma unroll
        for (int r = 0; r < 4; r++){
            int t = tid + r*256;
            int m = t >> 4, k = t & 15;
            int row = row0 + m;
            As[k*68 + m] = (row < M) ? A[(size_t)row*Kk + k0 + k] : 0.f;
        }
        #pragma unroll
        for (int r = 0; r < 4; r++){
            int t = tid + r*256;
            int k = t >> 6, n = t & 63;
            Bs[k*64 + n] = W[(size_t)(k0+k)*Nn + col0 + n];
        }
        __syncthreads();
        #pragma unroll
        for (int kk = 0; kk < 16; kk++){
            float4 a4 = *(const float4*)&As[kk*68 + ty*4];
            float4 b4 = *(const float4*)&Bs[kk*64 + tx*4];
            float av[4] = {a4.x, a4.y, a4.z, a4.w};
            float bv[4] = {b4.x, b4.y, b4.z, b4.w};
            #pragma unroll
            for (int i = 0; i < 4; i++)
                #pragma unroll
                for (int j = 0; j < 4; j++)
                    acc[i][j] += av[i]*bv[j];
        }
        __syncthreads();
    }
    #pragma unroll
    for (int i = 0; i < 4; i++){
        int row = row0 + ty*4 + i;
        if (row < M){
            #pragma unroll
            for (int j = 0; j < 4; j++){
                int col = col0 + tx*4 + j;
                float v = acc[i][j] + bias[col];
                if (pe) v += pe[(size_t)row*Nn + col];
                C[(size_t)row*Nn + col] = v;
            }
        }
    }
}

// fused Q/K/V/Skip projection: 4 weight matrices, N=2048 logical
__global__ __launch_bounds__(256) void gemm_qkvs(
    const float* __restrict__ A,
    const float* __restrict__ W0, const float* __restrict__ W1,
    const float* __restrict__ W2, const float* __restrict__ W3,
    const float* __restrict__ bb0, const float* __restrict__ bb1,
    const float* __restrict__ bb2, const float* __restrict__ bb3,
    float* __restrict__ C0, float* __restrict__ C1,
    float* __restrict__ C2, float* __restrict__ C3, int M)
{
    int mi = blockIdx.x >> 3;
    const float* W    = (mi==0)?W0 :(mi==1)?W1 :(mi==2)?W2 :W3;
    const float* bias = (mi==0)?bb0:(mi==1)?bb1:(mi==2)?bb2:bb3;
    float*       C    = (mi==0)?C0 :(mi==1)?C1 :(mi==2)?C2 :C3;
    int col0 = (blockIdx.x & 7)*64;
    int row0 = blockIdx.y*64;

    __shared__ float As[16*68];
    __shared__ float Bs[16*64];
    int tid = threadIdx.x;
    int tx = tid & 15, ty = tid >> 4;
    float acc[4][4] = {};
    for (int k0 = 0; k0 < 512; k0 += 16){
        #pragma unroll
        for (int r = 0; r < 4; r++){
            int t = tid + r*256;
            int m = t >> 4, k = t & 15;
            int row = row0 + m;
            As[k*68 + m] = (row < M) ? A[(size_t)row*512 + k0 + k] : 0.f;
        }
        #pragma unroll
        for (int r = 0; r < 4; r++){
            int t = tid + r*256;
            int k = t >> 6, n = t & 63;
            Bs[k*64 + n] = W[(size_t)(k0+k)*512 + col0 + n];
        }
        __syncthreads();
        #pragma unroll
        for (int kk = 0; kk < 16; kk++){
            float4 a4 = *(const float4*)&As[kk*68 + ty*4];
            float4 b4 = *(const float4*)&Bs[kk*64 + tx*4];
            float av[4] = {a4.x, a4.y, a4.z, a4.w};
            float bv[4] = {b4.x, b4.y, b4.z, b4.w};
            #pragma unroll
            for (int i = 0; i < 4; i++)
                #pragma unroll
                for (int j = 0; j < 4; j++)
                    acc[i][j] += av[i]*bv[j];
        }
        __syncthreads();
    }
    #pragma unroll
    for (int i = 0; i < 4; i++){
        int row = row0 + ty*4 + i;
        if (row < M){
            #pragma unroll
            for (int j = 0; j < 4; j++){
                int col = col0 + tx*4 + j;
                C[(size_t)row*512 + col] = acc[i][j] + bias[col];
            }
        }
    }
}

// ------------- fused per-node attention + softmax + skip + LayerNorm -------------
// one block (256 threads) per target node
__global__ __launch_bounds__(256) void attn_layer(
    const float* __restrict__ hcur,
    const float* __restrict__ Qm, const float* __restrict__ Km,
    const float* __restrict__ Vm, const float* __restrict__ SKm,
    const float* __restrict__ ef, const float* __restrict__ e_w_l,
    const float* __restrict__ ln_g_l, const float* __restrict__ ln_b_l,
    const int* __restrict__ ssrc, const int* __restrict__ seid,
    const int* __restrict__ offs, float* __restrict__ score_g,
    float* __restrict__ hnext)
{
    int tid = threadIdx.x;
    int t = blockIdx.x;

    __shared__ float q_s[512];
    __shared__ float qe_s[256];
    __shared__ float ef_s[1024];
    __shared__ float al_s[256];
    __shared__ float red[256];
    __shared__ float red2[256];
    __shared__ int   src_s[32];
    __shared__ int   eid_s[32];
    __shared__ float m_s[8];
    __shared__ float den_s[8];

    q_s[tid]       = Qm[(size_t)t*512 + tid];
    q_s[tid + 256] = Qm[(size_t)t*512 + 256 + tid];
    __syncthreads();

    // qe[h][d] = sum_c q[h*64+c] * e_w[d*512 + h*64 + c]
    {
        int hh = tid >> 5, dd = tid & 31;
        const float* wrow = e_w_l + (size_t)dd*512 + hh*64;
        const float* qh = q_s + hh*64;
        float acc = 0.f;
        #pragma unroll
        for (int c = 0; c < 64; c++) acc += qh[c]*wrow[c];
        qe_s[tid] = acc;
    }
    int start = offs[t];
    int deg = offs[t+1] - start;
    int h = tid & 7, ie = tid >> 3;
    float lmax = -1e30f;
    __syncthreads();

    // ---- phase A: scores + running max ----
    for (int cb = 0; cb < deg; cb += 32){
        int nn2 = min(32, deg - cb);
        if (tid < nn2){ src_s[tid] = ssrc[start+cb+tid]; eid_s[tid] = seid[start+cb+tid]; }
        __syncthreads();
        #pragma unroll
        for (int r = 0; r < 4; r++){
            int idx = tid + r*256;
            int e_i = idx >> 5, d = idx & 31;
            if (e_i < nn2) ef_s[idx] = ef[(size_t)eid_s[e_i]*32 + d];
        }
        __syncthreads();
        if (ie < nn2){
            int s = src_s[ie];
            const float4* kr = (const float4*)(Km + (size_t)s*512 + h*64);
            const float4* qr = (const float4*)(q_s + h*64);
            float sc = 0.f;
            #pragma unroll
            for (int c = 0; c < 16; c++){
                float4 a = qr[c], b = kr[c];
                sc += a.x*b.x + a.y*b.y + a.z*b.z + a.w*b.w;
            }
            const float* efr = ef_s + ie*32;
            const float* qer = qe_s + h*32;
            #pragma unroll
            for (int d = 0; d < 32; d++) sc += efr[d]*qer[d];
            sc *= SCALE;
            score_g[(size_t)(start+cb)*8 + tid] = sc;
            lmax = fmaxf(lmax, sc);
        }
        __syncthreads();
    }
    red[tid] = lmax;
    __syncthreads();
    if (tid < 8){
        float m = -1e30f;
        for (int i = tid; i < 256; i += 8) m = fmaxf(m, red[i]);
        m_s[tid] = m;
    }
    __syncthreads();

    // ---- phase B: exp, denominator, weighted accumulation ----
    float acc0 = 0.f, acc1 = 0.f, accE = 0.f, den0 = 0.f;
    int h0 = tid >> 6, h1 = 4 + (tid >> 6), h2 = tid >> 5;
    for (int cb = 0; cb < deg; cb += 32){
        int nn2 = min(32, deg - cb);
        if (tid < nn2){ src_s[tid] = ssrc[start+cb+tid]; eid_s[tid] = seid[start+cb+tid]; }
        __syncthreads();
        #pragma unroll
        for (int r = 0; r < 4; r++){
            int idx = tid + r*256;
            int e_i = idx >> 5, d = idx & 31;
            if (e_i < nn2) ef_s[idx] = ef[(size_t)eid_s[e_i]*32 + d];
        }
        float al = 0.f;
        if (ie < nn2){
            float sc = score_g[(size_t)(start+cb)*8 + tid];
            al = __expf(sc - m_s[h]);
        }
        al_s[tid] = al;
        den0 += al;
        __syncthreads();
        for (int i = 0; i < nn2; i++){
            int s = src_s[i];
            float a0 = al_s[i*8 + h0];
            float a1 = al_s[i*8 + h1];
            float a2 = al_s[i*8 + h2];
            acc0 += a0 * Vm[(size_t)s*512 + tid];
            acc1 += a1 * Vm[(size_t)s*512 + 256 + tid];
            accE += a2 * ef_s[i*32 + (tid & 31)];
        }
        __syncthreads();
    }
    red[tid] = den0;
    __syncthreads();
    if (tid < 8){
        float dsum = 0.f;
        for (int i = tid; i < 256; i += 8) dsum += red[i];
        den_s[tid] = dsum;
    }
    __syncthreads();

    float inv0 = 0.f, inv1 = 0.f, inv2 = 0.f;
    if (deg > 0){
        inv0 = 1.f/den_s[h0];
        inv1 = 1.f/den_s[h1];
        inv2 = 1.f/den_s[h2];
    }
    float r0 = acc0*inv0, r1 = acc1*inv1;
    al_s[tid] = accE*inv2;   // reuse al_s as normalized S[h][d]
    __syncthreads();

    // e-part of the message: S[h] @ e_w
    float oe0 = 0.f, oe1 = 0.f;
    {
        const float* a0p = al_s + h0*32;
        const float* a1p = al_s + h1*32;
        #pragma unroll
        for (int d = 0; d < 32; d++){
            oe0 += a0p[d]*e_w_l[(size_t)d*512 + tid];
            oe1 += a1p[d]*e_w_l[(size_t)d*512 + 256 + tid];
        }
    }
    float x0 = r0 + oe0 + SKm[(size_t)t*512 + tid]       + hcur[(size_t)t*512 + tid];
    float x1 = r1 + oe1 + SKm[(size_t)t*512 + 256 + tid] + hcur[(size_t)t*512 + 256 + tid];

    // LayerNorm over 512
    red[tid]  = x0 + x1;
    red2[tid] = x0*x0 + x1*x1;
    __syncthreads();
    for (int st = 128; st > 0; st >>= 1){
        if (tid < st){ red[tid] += red[tid+st]; red2[tid] += red2[tid+st]; }
        __syncthreads();
    }
    float mu  = red[0]*(1.f/512.f);
    float var = red2[0]*(1.f/512.f) - mu*mu;
    float rstd = rsqrtf(var + 1e-5f);
    hnext[(size_t)t*512 + tid]       = (x0 - mu)*rstd*ln_g_l[tid]       + ln_b_l[tid];
    hnext[(size_t)t*512 + 256 + tid] = (x1 - mu)*rstd*ln_g_l[256+tid]   + ln_b_l[256+tid];
}

// ---------------- final head: dom + concat + MLP ----------------
__global__ __launch_bounds__(256) void final_head(
    const float* __restrict__ hin,
    const float* __restrict__ dom_w, const float* __restrict__ dom_b,
    const float* __restrict__ w1, const float* __restrict__ b1,
    const float* __restrict__ w2, const float* __restrict__ b2,
    float* __restrict__ out)
{
    int tid = threadIdx.x, t = blockIdx.x;
    __shared__ float h_s[512];
    __shared__ float dom_s[16];
    __shared__ float hid_s[256];
    __shared__ float red[256];
    h_s[tid]     = hin[(size_t)t*512 + tid];
    h_s[tid+256] = hin[(size_t)t*512 + 256 + tid];
    __syncthreads();
    if (tid < 16){
        float a = dom_b[tid];
        for (int i = 0; i < 512; i++) a += h_s[i]*dom_w[i*16 + tid];
        dom_s[tid] = a;
    }
    __syncthreads();
    float acc = b1[tid];
    for (int i = 0; i < 512; i++) acc += h_s[i]*w1[(size_t)i*256 + tid];
    #pragma unroll
    for (int i = 0; i < 16; i++) acc += dom_s[i]*w1[(size_t)(512+i)*256 + tid];
    hid_s[tid] = fmaxf(acc, 0.f);
    __syncthreads();
    int o = tid & 15, g = tid >> 4;
    float p = 0.f;
    #pragma unroll
    for (int j = 0; j < 16; j++) p += hid_s[g*16 + j]*w2[(g*16 + j)*16 + o];
    red[tid] = p;
    __syncthreads();
    if (tid < 16){
        float s2 = b2[tid];
        for (int gg = 0; gg < 16; gg++) s2 += red[gg*16 + tid];
        out[(size_t)t*16 + tid] = s2;
    }
}

// ---------------- launch ----------------
extern "C" void kernel_launch(void* const* d_in, const int* in_sizes, int n_in,
                              void* d_out, int out_size, void* d_ws, size_t ws_size,
                              hipStream_t stream)
{
    const float* x       = (const float*)d_in[0];
    const int*   eidx    = (const int*)  d_in[1];
    const float* eattr   = (const float*)d_in[2];
    const float* embed_w = (const float*)d_in[3];
    const float* embed_b = (const float*)d_in[4];
    const float* pe      = (const float*)d_in[5];
    const float* ee_w1   = (const float*)d_in[6];
    const float* ee_b1   = (const float*)d_in[7];
    const float* ee_w2   = (const float*)d_in[8];
    const float* ee_b2   = (const float*)d_in[9];
    const float* q_w     = (const float*)d_in[10];
    const float* q_b     = (const float*)d_in[11];
    const float* k_w     = (const float*)d_in[12];
    const float* k_b     = (const float*)d_in[13];
    const float* v_w     = (const float*)d_in[14];
    const float* v_b     = (const float*)d_in[15];
    const float* e_w     = (const float*)d_in[16];
    const float* skip_w  = (const float*)d_in[17];
    const float* skip_b  = (const float*)d_in[18];
    const float* ln_g    = (const float*)d_in[19];
    const float* ln_b    = (const float*)d_in[20];
    const float* dom_w   = (const float*)d_in[21];
    const float* dom_b   = (const float*)d_in[22];
    const float* cls_w1  = (const float*)d_in[23];
    const float* cls_b1  = (const float*)d_in[24];
    const float* cls_w2  = (const float*)d_in[25];
    const float* cls_b2  = (const float*)d_in[26];
    float* out = (float*)d_out;

    float* ws = (float*)d_ws;
    size_t o = 0;
    float* h0    = ws + o; o += (size_t)HIDD*NN;
    float* h1    = ws + o; o += (size_t)HIDD*NN;
    float* Qb    = ws + o; o += (size_t)HIDD*NN;
    float* Kb    = ws + o; o += (size_t)HIDD*NN;
    float* Vb    = ws + o; o += (size_t)HIDD*NN;
    float* Sb    = ws + o; o += (size_t)HIDD*NN;
    float* efb   = ws + o; o += (size_t)32*EE;
    float* score = ws + o; o += (size_t)8*EE;
    int* cnt    = (int*)(ws + o); o += 1024;
    int* offs   = (int*)(ws + o); o += 1024;
    int* cursor = (int*)(ws + o); o += 1024;
    int* ssrc   = (int*)(ws + o); o += EE;
    int* seid   = (int*)(ws + o); o += EE;

    const int* srcp = eidx;
    const int* tgtp = eidx + EE;

    zero_counts<<<1, 1024, 0, stream>>>(cnt);
    hist_kernel<<<EE/256, 256, 0, stream>>>(tgtp, cnt);
    scan_kernel<<<1, 1024, 0, stream>>>(cnt, offs, cursor);
    scatter_kernel<<<EE/256, 256, 0, stream>>>(srcp, tgtp, cursor, ssrc, seid);
    edge_enc<<<EE/256, 256, 0, stream>>>(eattr, ee_w1, ee_b1, ee_w2, ee_b2, efb);
    gemm_embed<<<dim3(8, 16), 256, 0, stream>>>(x, embed_w, embed_b, pe, h0, NN, 512, 256);

    float* hc = h0;
    float* hn = h1;
    for (int l = 0; l < LAYERS; l++){
        gemm_qkvs<<<dim3(32, 16), 256, 0, stream>>>(
            hc,
            q_w + (size_t)l*512*512, k_w + (size_t)l*512*512,
            v_w + (size_t)l*512*512, skip_w + (size_t)l*512*512,
            q_b + (size_t)l*512, k_b + (size_t)l*512,
            v_b + (size_t)l*512, skip_b + (size_t)l*512,
            Qb, Kb, Vb, Sb, NN);
        attn_layer<<<NN, 256, 0, stream>>>(
            hc, Qb, Kb, Vb, Sb, efb, e_w + (size_t)l*32*512,
            ln_g + (size_t)l*512, ln_b + (size_t)l*512,
            ssrc, seid, offs, score, hn);
        float* tmp = hc; hc = hn; hn = tmp;
    }
    final_head<<<NN, 256, 0, stream>>>(hc, dom_w, dom_b, cls_w1, cls_b1, cls_w2, cls_b2, out);
}